// Round 1
// baseline (84.618 us; speedup 1.0000x reference)
//
#include <hip/hip_runtime.h>
#include <hip/hip_bf16.h>

#define BETA_INV 12.5f
#define EPS_NRM 1e-8f
#define NPAIR 4096
#define DDIM 256
#define MROWS 8192   // 2N

typedef __attribute__((ext_vector_type(8))) short bf16x8;   // 8 bf16 = 4 VGPRs
typedef __attribute__((ext_vector_type(4))) float f32x4;

// ---------------------------------------------------------------------------
// Kernel 1: row-pair normalize. One wave per pair i: computes ||x1_i||, ||x2_i||,
// x1_i . x2_i in f32; writes zn[i] (bf16), zn[i+N] (bf16), pos_half[i].
// ---------------------------------------------------------------------------
__global__ __launch_bounds__(256) void cl_normalize(
    const float* __restrict__ x1, const float* __restrict__ x2,
    ushort* __restrict__ zn, float* __restrict__ pos_half) {
  int wid  = threadIdx.x >> 6;
  int lane = threadIdx.x & 63;
  int row  = blockIdx.x * 4 + wid;           // pair index in [0, 4096)
  const float4* p1 = (const float4*)(x1 + row * DDIM);
  const float4* p2 = (const float4*)(x2 + row * DDIM);
  float4 a = p1[lane];
  float4 b = p2[lane];
  float s11 = a.x*a.x + a.y*a.y + a.z*a.z + a.w*a.w;
  float s22 = b.x*b.x + b.y*b.y + b.z*b.z + b.w*b.w;
  float s12 = a.x*b.x + a.y*b.y + a.z*b.z + a.w*b.w;
  #pragma unroll
  for (int m = 1; m < 64; m <<= 1) {
    s11 += __shfl_xor(s11, m);
    s22 += __shfl_xor(s22, m);
    s12 += __shfl_xor(s12, m);
  }
  float r1 = fmaxf(sqrtf(s11), EPS_NRM);
  float r2 = fmaxf(sqrtf(s22), EPS_NRM);
  float i1 = 1.0f / r1, i2 = 1.0f / r2;

  union { ushort4 u; __hip_bfloat16 h[4]; } w1, w2;
  w1.h[0] = __float2bfloat16(a.x * i1); w1.h[1] = __float2bfloat16(a.y * i1);
  w1.h[2] = __float2bfloat16(a.z * i1); w1.h[3] = __float2bfloat16(a.w * i1);
  w2.h[0] = __float2bfloat16(b.x * i2); w2.h[1] = __float2bfloat16(b.y * i2);
  w2.h[2] = __float2bfloat16(b.z * i2); w2.h[3] = __float2bfloat16(b.w * i2);
  *(ushort4*)(zn + row * DDIM + lane * 4)            = w1.u;
  *(ushort4*)(zn + (row + NPAIR) * DDIM + lane * 4)  = w2.u;

  if (lane == 0) pos_half[row] = s12 * i1 * i2 * BETA_INV;
}

// ---------------------------------------------------------------------------
// Kernel 2: Gram tile + exp + masked row-sum.
// 128x128 output tile, BK=64, 4 waves; each wave owns 32 rows x 128 cols
// (2 row-frags x 8 col-frags of 16x16, acc f32x4 each).
// LDS tiles XOR-swizzled (slot ^= row&7) to kill the stride-128B conflict.
// ---------------------------------------------------------------------------
__global__ __launch_bounds__(256) void cl_gram_expsum(
    const ushort* __restrict__ zn, float* __restrict__ denom) {
  const int BK = 64;
  int brow = blockIdx.y * 128;
  int bcol = blockIdx.x * 128;
  __shared__ ushort As[128 * BK];
  __shared__ ushort Bs[128 * BK];

  int tid  = threadIdx.x;
  int wid  = tid >> 6;
  int lane = tid & 63;
  int l15  = lane & 15;
  int lg   = lane >> 4;

  f32x4 acc[2][8];
  #pragma unroll
  for (int rt = 0; rt < 2; ++rt)
    #pragma unroll
    for (int ct = 0; ct < 8; ++ct)
      acc[rt][ct] = (f32x4){0.f, 0.f, 0.f, 0.f};

  for (int kc = 0; kc < DDIM / BK; ++kc) {
    __syncthreads();
    // stage A (rows brow..+128) and B (rows bcol..+128), k-chunk kc*64..+64
    #pragma unroll
    for (int it = 0; it < 4; ++it) {
      int slot = tid + 256 * it;     // 0..1023 : 128 rows x 8 x 16B
      int r = slot >> 3, s = slot & 7;
      int sw = (s ^ (r & 7)) * 8;    // swizzled ushort offset within row
      *(bf16x8*)(As + r * BK + sw) =
          *(const bf16x8*)(zn + (brow + r) * DDIM + kc * BK + s * 8);
      *(bf16x8*)(Bs + r * BK + sw) =
          *(const bf16x8*)(zn + (bcol + r) * DDIM + kc * BK + s * 8);
    }
    __syncthreads();

    #pragma unroll
    for (int ks = 0; ks < 2; ++ks) {
      int kslot = ks * 4 + lg;       // 16B slot index of this lane's k-chunk
      bf16x8 af[2], bfv[8];
      #pragma unroll
      for (int rt = 0; rt < 2; ++rt) {
        int r = 32 * wid + 16 * rt + l15;
        af[rt] = *(const bf16x8*)(As + r * BK + ((kslot ^ (r & 7)) * 8));
      }
      #pragma unroll
      for (int ct = 0; ct < 8; ++ct) {
        int c = 16 * ct + l15;
        bfv[ct] = *(const bf16x8*)(Bs + c * BK + ((kslot ^ (c & 7)) * 8));
      }
      #pragma unroll
      for (int rt = 0; rt < 2; ++rt)
        #pragma unroll
        for (int ct = 0; ct < 8; ++ct)
          acc[rt][ct] = __builtin_amdgcn_mfma_f32_16x16x32_bf16(
              af[rt], bfv[ct], acc[rt][ct], 0, 0, 0);
    }
  }

  // epilogue: exp, mask diagonal, row-sum across the 128 cols of this block
  #pragma unroll
  for (int rt = 0; rt < 2; ++rt) {
    int grow_base = brow + 32 * wid + 16 * rt + lg * 4;
    #pragma unroll
    for (int reg = 0; reg < 4; ++reg) {
      int grow = grow_base + reg;
      float s = 0.f;
      #pragma unroll
      for (int ct = 0; ct < 8; ++ct) {
        int gcol = bcol + 16 * ct + l15;
        float v = acc[rt][ct][reg];
        if (grow != gcol) s += __expf(v * BETA_INV);
      }
      s += __shfl_xor(s, 1);
      s += __shfl_xor(s, 2);
      s += __shfl_xor(s, 4);
      s += __shfl_xor(s, 8);
      if (l15 == 0) atomicAdd(&denom[grow], s);
    }
  }
}

// ---------------------------------------------------------------------------
// Kernel 3: loss = (sum_i log(denom_i) - 2 * sum_i pos_half_i) / 8192
// ---------------------------------------------------------------------------
__global__ __launch_bounds__(256) void cl_finalize(
    const float* __restrict__ denom, const float* __restrict__ pos_half,
    float* __restrict__ out) {
  float s = 0.f, p = 0.f;
  for (int i = threadIdx.x; i < MROWS; i += 256) s += logf(denom[i]);
  for (int i = threadIdx.x; i < NPAIR; i += 256) p += pos_half[i];
  #pragma unroll
  for (int m = 1; m < 64; m <<= 1) {
    s += __shfl_xor(s, m);
    p += __shfl_xor(p, m);
  }
  __shared__ float red[2][4];
  int wid = threadIdx.x >> 6, lane = threadIdx.x & 63;
  if (lane == 0) { red[0][wid] = s; red[1][wid] = p; }
  __syncthreads();
  if (threadIdx.x == 0) {
    float S = red[0][0] + red[0][1] + red[0][2] + red[0][3];
    float P = red[1][0] + red[1][1] + red[1][2] + red[1][3];
    out[0] = (S - 2.f * P) / (float)MROWS;
  }
}

extern "C" void kernel_launch(void* const* d_in, const int* in_sizes, int n_in,
                              void* d_out, int out_size, void* d_ws, size_t ws_size,
                              hipStream_t stream) {
  const float* x1 = (const float*)d_in[0];
  const float* x2 = (const float*)d_in[1];
  float* out = (float*)d_out;

  char* ws = (char*)d_ws;
  ushort* zn      = (ushort*)ws;                                 // 4 MiB bf16
  float*  denom   = (float*)(ws + (size_t)MROWS * DDIM * 2);     // 32 KiB
  float*  posh    = (float*)(ws + (size_t)MROWS * DDIM * 2 + MROWS * 4);

  hipMemsetAsync(denom, 0, MROWS * sizeof(float), stream);
  cl_normalize<<<NPAIR / 4, 256, 0, stream>>>(x1, x2, zn, posh);
  dim3 grid(MROWS / 128, MROWS / 128);
  cl_gram_expsum<<<grid, 256, 0, stream>>>(zn, denom);
  cl_finalize<<<1, 256, 0, stream>>>(denom, posh, out);
}

// Round 2
// 54.115 us; speedup vs baseline: 1.5637x; 1.5637x over previous
//
#include <hip/hip_runtime.h>
#include <hip/hip_bf16.h>

#define BETA_INV 12.5f
#define EPS_NRM 1e-8f
#define NPAIR 4096
#define DDIM 256
#define MROWS 8192   // 2N
#define NTILE 64     // 8192 / 128
#define NBLK (NTILE * (NTILE + 1) / 2)   // 2080 upper-triangle tiles

typedef __attribute__((ext_vector_type(8))) short bf16x8;   // 8 bf16 = 4 VGPRs
typedef __attribute__((ext_vector_type(4))) float f32x4;

// ---------------------------------------------------------------------------
// Kernel 1: row-pair normalize. One wave per pair i: computes ||x1_i||, ||x2_i||,
// x1_i . x2_i in f32; writes zn[i] (bf16), zn[i+N] (bf16), pos_half[i].
// Also zeroes denom[] (first 32 blocks) so no separate memset dispatch.
// ---------------------------------------------------------------------------
__global__ __launch_bounds__(256) void cl_normalize(
    const float* __restrict__ x1, const float* __restrict__ x2,
    ushort* __restrict__ zn, float* __restrict__ pos_half,
    float* __restrict__ denom) {
  if (blockIdx.x < 32) denom[blockIdx.x * 256 + threadIdx.x] = 0.0f;

  int wid  = threadIdx.x >> 6;
  int lane = threadIdx.x & 63;
  int row  = blockIdx.x * 4 + wid;           // pair index in [0, 4096)
  const float4* p1 = (const float4*)(x1 + row * DDIM);
  const float4* p2 = (const float4*)(x2 + row * DDIM);
  float4 a = p1[lane];
  float4 b = p2[lane];
  float s11 = a.x*a.x + a.y*a.y + a.z*a.z + a.w*a.w;
  float s22 = b.x*b.x + b.y*b.y + b.z*b.z + b.w*b.w;
  float s12 = a.x*b.x + a.y*b.y + a.z*b.z + a.w*b.w;
  #pragma unroll
  for (int m = 1; m < 64; m <<= 1) {
    s11 += __shfl_xor(s11, m);
    s22 += __shfl_xor(s22, m);
    s12 += __shfl_xor(s12, m);
  }
  float r1 = fmaxf(sqrtf(s11), EPS_NRM);
  float r2 = fmaxf(sqrtf(s22), EPS_NRM);
  float i1 = 1.0f / r1, i2 = 1.0f / r2;

  union { ushort4 u; __hip_bfloat16 h[4]; } w1, w2;
  w1.h[0] = __float2bfloat16(a.x * i1); w1.h[1] = __float2bfloat16(a.y * i1);
  w1.h[2] = __float2bfloat16(a.z * i1); w1.h[3] = __float2bfloat16(a.w * i1);
  w2.h[0] = __float2bfloat16(b.x * i2); w2.h[1] = __float2bfloat16(b.y * i2);
  w2.h[2] = __float2bfloat16(b.z * i2); w2.h[3] = __float2bfloat16(b.w * i2);
  *(ushort4*)(zn + row * DDIM + lane * 4)            = w1.u;
  *(ushort4*)(zn + (row + NPAIR) * DDIM + lane * 4)  = w2.u;

  if (lane == 0) pos_half[row] = s12 * i1 * i2 * BETA_INV;
}

// ---------------------------------------------------------------------------
// Kernel 2: symmetric Gram tile + exp + masked row/col sums.
// Only upper-triangle 128x128 tiles (2080 blocks). Off-diagonal tiles feed
// exp(sim_ij) into BOTH denom[row] and denom[col] (symmetry), halving MFMA
// and exp work vs the full grid. Diagonal tiles: diag-masked row-sums only.
// LDS tiles XOR-swizzled (slot ^= row&7) to kill the stride-128B conflict.
// ---------------------------------------------------------------------------
__global__ __launch_bounds__(256) void cl_gram_expsum(
    const ushort* __restrict__ zn, float* __restrict__ denom) {
  const int BK = 64;
  // decode linear block id -> (i, j) with i <= j in the tile upper triangle
  int idx = blockIdx.x;
  int j = (int)((sqrtf(8.0f * idx + 1.0f) - 1.0f) * 0.5f);
  while ((j + 1) * (j + 2) / 2 <= idx) ++j;
  while (j * (j + 1) / 2 > idx) --j;
  int i = idx - j * (j + 1) / 2;
  int brow = i * 128;
  int bcol = j * 128;

  __shared__ ushort As[128 * BK];
  __shared__ ushort Bs[128 * BK];

  int tid  = threadIdx.x;
  int wid  = tid >> 6;
  int lane = tid & 63;
  int l15  = lane & 15;
  int lg   = lane >> 4;

  f32x4 acc[2][8];
  #pragma unroll
  for (int rt = 0; rt < 2; ++rt)
    #pragma unroll
    for (int ct = 0; ct < 8; ++ct)
      acc[rt][ct] = (f32x4){0.f, 0.f, 0.f, 0.f};

  for (int kc = 0; kc < DDIM / BK; ++kc) {
    __syncthreads();
    // stage A (rows brow..+128) and B (rows bcol..+128), k-chunk kc*64..+64
    #pragma unroll
    for (int it = 0; it < 4; ++it) {
      int slot = tid + 256 * it;     // 0..1023 : 128 rows x 8 x 16B
      int r = slot >> 3, s = slot & 7;
      int sw = (s ^ (r & 7)) * 8;    // swizzled ushort offset within row
      *(bf16x8*)(As + r * BK + sw) =
          *(const bf16x8*)(zn + (brow + r) * DDIM + kc * BK + s * 8);
      *(bf16x8*)(Bs + r * BK + sw) =
          *(const bf16x8*)(zn + (bcol + r) * DDIM + kc * BK + s * 8);
    }
    __syncthreads();

    #pragma unroll
    for (int ks = 0; ks < 2; ++ks) {
      int kslot = ks * 4 + lg;       // 16B slot index of this lane's k-chunk
      bf16x8 af[2], bfv[8];
      #pragma unroll
      for (int rt = 0; rt < 2; ++rt) {
        int r = 32 * wid + 16 * rt + l15;
        af[rt] = *(const bf16x8*)(As + r * BK + ((kslot ^ (r & 7)) * 8));
      }
      #pragma unroll
      for (int ct = 0; ct < 8; ++ct) {
        int c = 16 * ct + l15;
        bfv[ct] = *(const bf16x8*)(Bs + c * BK + ((kslot ^ (c & 7)) * 8));
      }
      #pragma unroll
      for (int rt = 0; rt < 2; ++rt)
        #pragma unroll
        for (int ct = 0; ct < 8; ++ct)
          acc[rt][ct] = __builtin_amdgcn_mfma_f32_16x16x32_bf16(
              af[rt], bfv[ct], acc[rt][ct], 0, 0, 0);
    }
  }

  __syncthreads();   // everyone done reading As/Bs (As is reused below)

  if (brow == bcol) {
    // diagonal tile: mask the true diagonal; row-sums only (cols are the
    // same index set -> already covered by this tile's row sums)
    #pragma unroll
    for (int rt = 0; rt < 2; ++rt) {
      int grow_base = brow + 32 * wid + 16 * rt + lg * 4;
      #pragma unroll
      for (int reg = 0; reg < 4; ++reg) {
        int grow = grow_base + reg;
        float s = 0.f;
        #pragma unroll
        for (int ct = 0; ct < 8; ++ct) {
          int gcol = bcol + 16 * ct + l15;
          if (grow != gcol) s += __expf(acc[rt][ct][reg] * BETA_INV);
        }
        s += __shfl_xor(s, 1);
        s += __shfl_xor(s, 2);
        s += __shfl_xor(s, 4);
        s += __shfl_xor(s, 8);
        if (l15 == 0) atomicAdd(&denom[grow], s);
      }
    }
  } else {
    // off-diagonal tile: every exp feeds a row-sum AND a col-sum
    float csum[8];
    #pragma unroll
    for (int ct = 0; ct < 8; ++ct) csum[ct] = 0.f;

    #pragma unroll
    for (int rt = 0; rt < 2; ++rt) {
      int grow_base = brow + 32 * wid + 16 * rt + lg * 4;
      #pragma unroll
      for (int reg = 0; reg < 4; ++reg) {
        float s = 0.f;
        #pragma unroll
        for (int ct = 0; ct < 8; ++ct) {
          float e = __expf(acc[rt][ct][reg] * BETA_INV);
          s += e;
          csum[ct] += e;
        }
        s += __shfl_xor(s, 1);
        s += __shfl_xor(s, 2);
        s += __shfl_xor(s, 4);
        s += __shfl_xor(s, 8);
        if (l15 == 0) atomicAdd(&denom[grow_base + reg], s);
      }
    }

    // col-sums: reduce across the 4 lane-groups (rows) within the wave,
    // then across the 4 waves via LDS (reusing As), then 128 atomics.
    float* colred = (float*)As;        // [4][128] floats = 2 KiB
    #pragma unroll
    for (int ct = 0; ct < 8; ++ct) {
      float c = csum[ct];
      c += __shfl_xor(c, 16);
      c += __shfl_xor(c, 32);
      if (lg == 0) colred[wid * 128 + ct * 16 + l15] = c;
    }
    __syncthreads();
    if (tid < 128) {
      float c = colred[tid] + colred[128 + tid] + colred[256 + tid] +
                colred[384 + tid];
      atomicAdd(&denom[bcol + tid], c);
    }
  }
}

// ---------------------------------------------------------------------------
// Kernel 3: loss = (sum_i log(denom_i) - 2 * sum_i pos_half_i) / 8192
// ---------------------------------------------------------------------------
__global__ __launch_bounds__(1024) void cl_finalize(
    const float* __restrict__ denom, const float* __restrict__ pos_half,
    float* __restrict__ out) {
  float s = 0.f, p = 0.f;
  for (int i = threadIdx.x; i < MROWS; i += 1024) s += logf(denom[i]);
  for (int i = threadIdx.x; i < NPAIR; i += 1024) p += pos_half[i];
  #pragma unroll
  for (int m = 1; m < 64; m <<= 1) {
    s += __shfl_xor(s, m);
    p += __shfl_xor(p, m);
  }
  __shared__ float red[2][16];
  int wid = threadIdx.x >> 6, lane = threadIdx.x & 63;
  if (lane == 0) { red[0][wid] = s; red[1][wid] = p; }
  __syncthreads();
  if (threadIdx.x == 0) {
    float S = 0.f, P = 0.f;
    #pragma unroll
    for (int w = 0; w < 16; ++w) { S += red[0][w]; P += red[1][w]; }
    out[0] = (S - 2.f * P) / (float)MROWS;
  }
}

extern "C" void kernel_launch(void* const* d_in, const int* in_sizes, int n_in,
                              void* d_out, int out_size, void* d_ws, size_t ws_size,
                              hipStream_t stream) {
  const float* x1 = (const float*)d_in[0];
  const float* x2 = (const float*)d_in[1];
  float* out = (float*)d_out;

  char* ws = (char*)d_ws;
  ushort* zn      = (ushort*)ws;                                 // 4 MiB bf16
  float*  denom   = (float*)(ws + (size_t)MROWS * DDIM * 2);     // 32 KiB
  float*  posh    = (float*)(ws + (size_t)MROWS * DDIM * 2 + MROWS * 4);

  cl_normalize<<<NPAIR / 4, 256, 0, stream>>>(x1, x2, zn, posh, denom);
  cl_gram_expsum<<<NBLK, 256, 0, stream>>>(zn, denom);
  cl_finalize<<<1, 1024, 0, stream>>>(denom, posh, out);
}